// Round 3
// baseline (804.950 us; speedup 1.0000x reference)
//
#include <hip/hip_runtime.h>
#include <hip/hip_fp16.h>
#include <math.h>

// ESN: FFT(262144) over 32 cols -> fused(proj -> chunked tanh scan -> out matmul)
//      -> IFFT, REAL part only to d_out as float32 [T,32].
//
// Budget: d_out = 33.5 MB (float [T,32]); peak d_ws = 67 MB (one complex region).
// Forward FFT pass B runs in-place on ws (Xc left digit-swapped); outc stored
// fp16 in d_out; inverse writes real part only.
//
// v4 scan kernel: CPB=1 (SCH=64, grid 4096). LDS = 37,536 B -> 4 blocks/CU
// (16 waves/CU vs v3's 8): v3 post-mortem showed the scan chain is only
// ~35 us; the ~310 us remainder is Phases A/C at VALUBusy 19% / Occ 22% --
// latency-bound with too few waves. 4 blocks/CU doubles issue slots and lets
// other blocks' A/C overlap each scan. Phase A additionally splits each row
// across 2 threads (r-halves) -> 184/256 active lanes, half per-thread depth.

constexpr int TLEN = 262144;   // 2^18 = 512*512
constexpr int NCOL = 32;       // IN == OUT == 32 columns
constexpr int NR = 50;         // reservoir size
constexpr int SCH = 64;        // scan chunk length (4096 chunks)
constexpr int LW = 28;         // scan warmup rows (validated: absmax unchanged vs 32)
constexpr int ROWS = SCH + LW; // 92 rows per chunk buffer
constexpr int LDSTR = 51;      // LDS row stride in float2 (odd -> fewer conflicts)
constexpr float TWO_PI = 6.28318530717958647692f;

__device__ __forceinline__ unsigned rev9(unsigned x) { return __brev(x) >> 23; }

// In-LDS 512-point radix-2 DIT FFT on 16 interleaved columns.
// lds[512][16], input must be bit-reversed (rev9) on load. 256 threads.
template <int SIGN>
__device__ __forceinline__ void fft512(float2 (*lds)[16], int tid) {
  const int cl = tid & 15;
  const int bb = tid >> 4;
#pragma unroll
  for (int s = 1; s <= 9; ++s) {
    const int half = 1 << (s - 1);
    const float invm = 1.0f / (float)(1 << s);
#pragma unroll
    for (int i = 0; i < 16; ++i) {
      const int b = bb + (i << 4);            // butterfly slot 0..255
      const int j = b & (half - 1);
      const int g = b >> (s - 1);
      const int i1 = (g << s) + j;
      const int i2 = i1 + half;
      float2 a = lds[i1][cl];
      float2 c = lds[i2][cl];
      float ang = (float)SIGN * TWO_PI * ((float)j * invm);  // j/m exact
      float sw, cw;
      __sincosf(ang, &sw, &cw);
      float2 t = make_float2(c.x * cw - c.y * sw, c.x * sw + c.y * cw);
      lds[i1][cl] = make_float2(a.x + t.x, a.y + t.y);
      lds[i2][cl] = make_float2(a.x - t.x, a.y - t.y);
    }
    __syncthreads();
  }
}

// Pass A: input index n = nL + 512*nH; for block nL, FFT over nH -> kL,
// apply twiddle e^{SIGN*2pi*i*nL*kL/T}, store I[kL][nL] at ws row (kL*512+nL).
// INMODE 0: real float input (forward, X). INMODE 1: half2 complex input
// (inverse, outc in d_out), scaled by `scale` (1/T folded here).
template <int SIGN, int INMODE>
__global__ __launch_bounds__(256) void fft_passA(const void* __restrict__ vin,
                                                 float2* __restrict__ out,
                                                 float scale) {
  __shared__ float2 lds[512][16];
  const int nL = blockIdx.x;
  const int cg = blockIdx.y;
  const int tid = threadIdx.x;
  const int cl = tid & 15;
  const int cglob = cg * 16 + cl;
#pragma unroll
  for (int i = 0; i < 32; ++i) {
    const int nH = (tid >> 4) + i * 16;
    const size_t gidx = (size_t)(nL + (nH << 9)) * NCOL + cglob;
    float2 v;
    if (INMODE == 0) {
      v = make_float2(((const float*)vin)[gidx], 0.0f);
    } else {
      const float2 f = __half22float2(((const __half2*)vin)[gidx]);
      v = make_float2(f.x * scale, f.y * scale);
    }
    lds[rev9(nH)][cl] = v;
  }
  __syncthreads();
  fft512<SIGN>(lds, tid);
#pragma unroll
  for (int i = 0; i < 32; ++i) {
    const int kL = (tid >> 4) + i * 16;
    float2 v = lds[kL][cl];
    const float rev = (float)(nL * kL) * (1.0f / 262144.0f);  // exact (<2^24 / 2^18)
    const float ang = (float)SIGN * TWO_PI * rev;
    float sw, cw;
    __sincosf(ang, &sw, &cw);
    float2 w = make_float2(v.x * cw - v.y * sw, v.x * sw + v.y * cw);
    out[(size_t)(kL * 512 + nL) * NCOL + cglob] = w;
  }
}

// Pass B: for block kL, FFT over nL (rows kL*512+nL) -> kH.
// REALOUT=false (forward): store IN-PLACE at row (kL*512+kH) -> digit-swapped.
// REALOUT=true (inverse): store real part only, natural order, float [T,32].
template <int SIGN, bool REALOUT>
__global__ __launch_bounds__(256) void fft_passB(float2* __restrict__ buf,
                                                 float* __restrict__ rout) {
  __shared__ float2 lds[512][16];
  const int kL = blockIdx.x;
  const int cg = blockIdx.y;
  const int tid = threadIdx.x;
  const int cl = tid & 15;
  const int cglob = cg * 16 + cl;
#pragma unroll
  for (int i = 0; i < 32; ++i) {
    const int nL = (tid >> 4) + i * 16;
    lds[rev9(nL)][cl] = buf[(size_t)(kL * 512 + nL) * NCOL + cglob];
  }
  __syncthreads();
  fft512<SIGN>(lds, tid);
#pragma unroll
  for (int i = 0; i < 32; ++i) {
    const int kH = (tid >> 4) + i * 16;
    if (REALOUT) {
      rout[(size_t)(kL + (kH << 9)) * NCOL + cglob] = lds[kH][cl].x;
    } else {
      buf[(size_t)(kL * 512 + kH) * NCOL + cglob] = lds[kH][cl];
    }
  }
}

// s' = ctanh(p + d*s);  ctanh(x+iy) = (sinh 2x + i sin 2y)/(cosh 2x + cos 2y)
__device__ __forceinline__ void esn_step(float d, float pr, float pi,
                                         float& sr, float& si) {
  const float x = fmaf(d, sr, pr);
  const float y = fmaf(d, si, pi);
  float x2 = 2.0f * x;
  x2 = fminf(fmaxf(x2, -30.0f), 30.0f);  // fp32-saturated beyond this
  const float E = __expf(x2);
  const float Ei = __expf(-x2);
  const float sh = 0.5f * (E - Ei);
  const float ch = 0.5f * (E + Ei);
  float s2, c2;
  __sincosf(2.0f * y, &s2, &c2);
  const float inv = __builtin_amdgcn_rcpf(ch + c2);
  sr = sh * inv;
  si = s2 * inv;
}

// Fused proj -> scan -> out matmul. 256 threads, ONE chunk of SCH=64 per block.
// Xc is digit-swapped: row of frequency k at ((k&511)<<9)|(k>>9).
// Phase A: threads [0,184): pair (row = tid>>1, half = tid&1) projects r-range
//          [half*25, half*25+25) of one row into LDS.
// Phase B: wave 0 scans with state in REGISTERS; proj rows read with a 3-deep
//          rotating prefetch (read of row i+3 issues before the in-place
//          state write of row i -> LDS latency hidden). Warmup LW=28 from
//          zero state; chunk 0 gets exact zero proj rows.
// Phase C: all 4 waves, 2 iterations: outc[t][o] = sum_r states[t][r]*Wout[o][r],
//          fp16 per-half2 stores (Wout from global/L1; no local arrays).
__global__ __launch_bounds__(256) void esn_scan_fused(
    const float2* __restrict__ Xc, const float* __restrict__ Win,
    const float* __restrict__ dvec, const float* __restrict__ Wout,
    __half2* __restrict__ outh) {
  __shared__ float2 proj[ROWS * LDSTR];  // 92*51*8 = 37,536 B -> 4 blocks/CU
  const int tid = threadIdx.x;

  // Phase A: 2 threads per row, disjoint r-halves [0,25) / [25,50).
  if (tid < 2 * ROWS) {
    const int row = tid >> 1;
    const int r0 = (tid & 1) * 25;
    const int t = blockIdx.x * SCH - LW + row;
    float2* dst = &proj[row * LDSTR];
    if (t < 0) {
      for (int r = r0; r < r0 + 25; ++r) dst[r] = make_float2(0.f, 0.f);
    } else {
      const size_t xrow = (size_t)(((t & 511) << 9) | (t >> 9));  // digit-swap
      const float4* src = (const float4*)(Xc + xrow * NCOL);      // 256B aligned
      float2 xc[NCOL];
#pragma unroll
      for (int i = 0; i < NCOL / 2; ++i) {
        float4 v = src[i];
        xc[2 * i] = make_float2(v.x, v.y);
        xc[2 * i + 1] = make_float2(v.z, v.w);
      }
      for (int r = r0; r < r0 + 25; ++r) {
        float pr = 0.f, pi = 0.f;
#pragma unroll
        for (int c = 0; c < NCOL; ++c) {
          const float w = Win[r * NCOL + c];  // uniform -> scalar broadcast
          pr = fmaf(w, xc[c].x, pr);
          pi = fmaf(w, xc[c].y, pi);
        }
        dst[r] = make_float2(pr, pi);
      }
    }
  }
  __syncthreads();

  // Phase B: register-state scan on wave 0.
  // Rotating 3-deep prefetch: row i+3 is read before row i's state write;
  // i+3 > i so no read-after-overwrite hazard. Tail clamps re-read row
  // ROWS-1, which is only written in the final iteration after its read.
  if (tid < 64) {
    const int lane = tid;
    const int rl = lane < NR ? lane : NR - 1;
    const float d = dvec[rl];
    float sr = 0.f, si = 0.f;
    float2 p0 = proj[0 * LDSTR + rl];
    float2 p1 = proj[1 * LDSTR + rl];
    float2 p2 = proj[2 * LDSTR + rl];
    for (int i = 0; i < ROWS; ++i) {
      const float2 p = p0;
      p0 = p1;
      p1 = p2;
      const int ip = (i + 3 < ROWS) ? (i + 3) : (ROWS - 1);
      p2 = proj[ip * LDSTR + rl];             // issued before the write below
      esn_step(d, p.x, p.y, sr, si);
      if (lane < NR) proj[i * LDSTR + lane] = make_float2(sr, si);
    }
  }
  __syncthreads();

  // Phase C: out matmul, fp16 complex stores (natural k-order rows).
#pragma unroll
  for (int k = 0; k < 2; ++k) {
    const int idx = tid + (k << 8);          // [0, 512) = 64 rows * 8 og
    const int tl = idx >> 3;                 // 0..63
    const int o0 = (idx & 7) << 2;           // 0,4,...,28
    const float2* srow = &proj[(LW + tl) * LDSTR];
    float ar[4] = {0.f, 0.f, 0.f, 0.f};
    float ai[4] = {0.f, 0.f, 0.f, 0.f};
    for (int r = 0; r < NR; ++r) {
      const float2 s = srow[r];
#pragma unroll
      for (int j = 0; j < 4; ++j) {
        const float w = Wout[(o0 + j) * NR + r];
        ar[j] = fmaf(w, s.x, ar[j]);
        ai[j] = fmaf(w, s.y, ai[j]);
      }
    }
#pragma unroll
    for (int j = 0; j < 4; ++j)
      outh[((size_t)blockIdx.x * SCH + tl) * NCOL + o0 + j] =
          __floats2half2_rn(ar[j], ai[j]);
  }
}

extern "C" void kernel_launch(void* const* d_in, const int* in_sizes, int n_in,
                              void* d_out, int out_size, void* d_ws, size_t ws_size,
                              hipStream_t stream) {
  const float* X = (const float*)d_in[0];      // [T,32] f32
  const float* Win = (const float*)d_in[1];    // [50,32] f32
  const float* dvec = (const float*)d_in[2];   // [50] f32
  const float* Wout = (const float*)d_in[3];   // [32,50] f32

  float2* Wa = (float2*)d_ws;                  // 67,108,864 B complex region
  dim3 fgrid(512, 2);

  // 1. fwd pass A: X (real) -> ws   (I[kL][nL] at row kL*512+nL)
  fft_passA<-1, 0><<<fgrid, 256, 0, stream>>>(X, Wa, 1.0f);
  // 2. fwd pass B: ws in-place      (Xc digit-swapped)
  fft_passB<-1, false><<<fgrid, 256, 0, stream>>>(Wa, nullptr);
  // 3. fused proj+scan+out: ws(Xc) -> d_out (outc, fp16 complex [T,32])
  esn_scan_fused<<<TLEN / SCH, 256, 0, stream>>>(Wa, Win, dvec, Wout,
                                                 (__half2*)d_out);
  // 4. inv pass A: d_out (fp16 outc) -> ws  (1/T folded into scale)
  fft_passA<1, 1><<<fgrid, 256, 0, stream>>>(d_out, Wa, 1.0f / 262144.0f);
  // 5. inv pass B: ws -> d_out, REAL part only, float32 [T,32]
  fft_passB<1, true><<<fgrid, 256, 0, stream>>>(Wa, (float*)d_out);

  (void)in_sizes; (void)n_in; (void)out_size; (void)ws_size;
}

// Round 4
// 720.006 us; speedup vs baseline: 1.1180x; 1.1180x over previous
//
#include <hip/hip_runtime.h>
#include <hip/hip_fp16.h>
#include <math.h>

// ESN: FFT(262144) over 32 cols -> fused(proj -> chunked tanh scan -> out matmul)
//      -> IFFT, REAL part only to d_out as float32 [T,32].
//
// v5 scan kernel: persistent-block 3-stage software pipeline. In round rr:
//   wave 0:    B (scan)    chunk rr-1  : projbuf[(rr-1)&1] -> statebuf[(rr-1)&1]
//   waves 1-3: A (project) chunk rr    : global Xc -> projbuf[rr&1]
//              C (matmul)  chunk rr-2  : statebuf[rr&1] -> outh
// Buffer parity makes all four concurrent accesses disjoint; ONE barrier per
// round. No wave ever parks during the scan (v1-v4: 3/4 waves idle at the
// B barrier -> >85% stall at 15-19% VALUBusy). B now reads a read-only LDS
// array (no in-place update) so the 3-deep register prefetch actually hides
// LDS latency (no conservative lgkmcnt(0) per step). A's global loads issue
// before C's fma block -> HBM latency hidden under compute.
// LDS = 2*37,536 + 2*26,112 = 127,296 B -> 1 block/CU, 512 persistent blocks
// x 8 chunks, 10 rounds each.

constexpr int TLEN = 262144;   // 2^18 = 512*512
constexpr int NCOL = 32;       // IN == OUT == 32 columns
constexpr int NR = 50;         // reservoir size
constexpr int SCH = 64;        // scan chunk length (4096 chunks)
constexpr int LW = 28;         // scan warmup rows (validated: absmax unchanged vs 32)
constexpr int ROWS = SCH + LW; // 92 rows per chunk buffer
constexpr int CPB = 8;         // chunks per persistent block (grid 512)
constexpr int LDSTR = 51;      // LDS row stride in float2 (odd -> fewer conflicts)
constexpr float TWO_PI = 6.28318530717958647692f;

__device__ __forceinline__ unsigned rev9(unsigned x) { return __brev(x) >> 23; }

// In-LDS 512-point radix-2 DIT FFT on 16 interleaved columns.
// lds[512][16], input must be bit-reversed (rev9) on load. 256 threads.
template <int SIGN>
__device__ __forceinline__ void fft512(float2 (*lds)[16], int tid) {
  const int cl = tid & 15;
  const int bb = tid >> 4;
#pragma unroll
  for (int s = 1; s <= 9; ++s) {
    const int half = 1 << (s - 1);
    const float invm = 1.0f / (float)(1 << s);
#pragma unroll
    for (int i = 0; i < 16; ++i) {
      const int b = bb + (i << 4);            // butterfly slot 0..255
      const int j = b & (half - 1);
      const int g = b >> (s - 1);
      const int i1 = (g << s) + j;
      const int i2 = i1 + half;
      float2 a = lds[i1][cl];
      float2 c = lds[i2][cl];
      float ang = (float)SIGN * TWO_PI * ((float)j * invm);  // j/m exact
      float sw, cw;
      __sincosf(ang, &sw, &cw);
      float2 t = make_float2(c.x * cw - c.y * sw, c.x * sw + c.y * cw);
      lds[i1][cl] = make_float2(a.x + t.x, a.y + t.y);
      lds[i2][cl] = make_float2(a.x - t.x, a.y - t.y);
    }
    __syncthreads();
  }
}

// Pass A: input index n = nL + 512*nH; for block nL, FFT over nH -> kL,
// apply twiddle e^{SIGN*2pi*i*nL*kL/T}, store I[kL][nL] at ws row (kL*512+nL).
// INMODE 0: real float input (forward, X). INMODE 1: half2 complex input
// (inverse, outc in d_out), scaled by `scale` (1/T folded here).
template <int SIGN, int INMODE>
__global__ __launch_bounds__(256) void fft_passA(const void* __restrict__ vin,
                                                 float2* __restrict__ out,
                                                 float scale) {
  __shared__ float2 lds[512][16];
  const int nL = blockIdx.x;
  const int cg = blockIdx.y;
  const int tid = threadIdx.x;
  const int cl = tid & 15;
  const int cglob = cg * 16 + cl;
#pragma unroll
  for (int i = 0; i < 32; ++i) {
    const int nH = (tid >> 4) + i * 16;
    const size_t gidx = (size_t)(nL + (nH << 9)) * NCOL + cglob;
    float2 v;
    if (INMODE == 0) {
      v = make_float2(((const float*)vin)[gidx], 0.0f);
    } else {
      const float2 f = __half22float2(((const __half2*)vin)[gidx]);
      v = make_float2(f.x * scale, f.y * scale);
    }
    lds[rev9(nH)][cl] = v;
  }
  __syncthreads();
  fft512<SIGN>(lds, tid);
#pragma unroll
  for (int i = 0; i < 32; ++i) {
    const int kL = (tid >> 4) + i * 16;
    float2 v = lds[kL][cl];
    const float rev = (float)(nL * kL) * (1.0f / 262144.0f);  // exact (<2^24 / 2^18)
    const float ang = (float)SIGN * TWO_PI * rev;
    float sw, cw;
    __sincosf(ang, &sw, &cw);
    float2 w = make_float2(v.x * cw - v.y * sw, v.x * sw + v.y * cw);
    out[(size_t)(kL * 512 + nL) * NCOL + cglob] = w;
  }
}

// Pass B: for block kL, FFT over nL (rows kL*512+nL) -> kH.
// REALOUT=false (forward): store IN-PLACE at row (kL*512+kH) -> digit-swapped.
// REALOUT=true (inverse): store real part only, natural order, float [T,32].
template <int SIGN, bool REALOUT>
__global__ __launch_bounds__(256) void fft_passB(float2* __restrict__ buf,
                                                 float* __restrict__ rout) {
  __shared__ float2 lds[512][16];
  const int kL = blockIdx.x;
  const int cg = blockIdx.y;
  const int tid = threadIdx.x;
  const int cl = tid & 15;
  const int cglob = cg * 16 + cl;
#pragma unroll
  for (int i = 0; i < 32; ++i) {
    const int nL = (tid >> 4) + i * 16;
    lds[rev9(nL)][cl] = buf[(size_t)(kL * 512 + nL) * NCOL + cglob];
  }
  __syncthreads();
  fft512<SIGN>(lds, tid);
#pragma unroll
  for (int i = 0; i < 32; ++i) {
    const int kH = (tid >> 4) + i * 16;
    if (REALOUT) {
      rout[(size_t)(kL + (kH << 9)) * NCOL + cglob] = lds[kH][cl].x;
    } else {
      buf[(size_t)(kL * 512 + kH) * NCOL + cglob] = lds[kH][cl];
    }
  }
}

// s' = ctanh(p + d*s);  ctanh(x+iy) = (sinh 2x + i sin 2y)/(cosh 2x + cos 2y)
__device__ __forceinline__ void esn_step(float d, float pr, float pi,
                                         float& sr, float& si) {
  const float x = fmaf(d, sr, pr);
  const float y = fmaf(d, si, pi);
  float x2 = 2.0f * x;
  x2 = fminf(fmaxf(x2, -30.0f), 30.0f);  // fp32-saturated beyond this
  const float E = __expf(x2);
  const float Ei = __expf(-x2);
  const float sh = 0.5f * (E - Ei);
  const float ch = 0.5f * (E + Ei);
  float s2, c2;
  __sincosf(2.0f * y, &s2, &c2);
  const float inv = __builtin_amdgcn_rcpf(ch + c2);
  sr = sh * inv;
  si = s2 * inv;
}

// Persistent pipelined fused kernel. 256 threads, CPB chunks per block.
// Xc is digit-swapped: row of frequency k at ((k&511)<<9)|(k>>9).
__global__ __launch_bounds__(256) void esn_scan_fused(
    const float2* __restrict__ Xc, const float* __restrict__ Win,
    const float* __restrict__ dvec, const float* __restrict__ Wout,
    __half2* __restrict__ outh) {
  __shared__ float2 projbuf[2][ROWS * LDSTR];  // 2*92*51*8 = 75,072 B
  __shared__ float2 statebuf[2][SCH * LDSTR];  // 2*64*51*8 = 52,224 B (tot 127,296)
  const int tid = threadIdx.x;
  const int cbase = blockIdx.x * CPB;

  // Wave-0 scan constants (computed by all threads; only wave 0 uses them).
  const int lane = tid & 63;
  const int rl = lane < NR ? lane : NR - 1;
  const float dv = dvec[rl];

  for (int rr = 0; rr < CPB + 2; ++rr) {
    if (tid >= 64) {
      const int sub = tid - 64;              // 0..191 (waves 1-3)

      // ---- A (stage 1 of pipeline): issue loads for chunk cbase+rr -------
      const bool aAct = (rr < CPB) && (sub < 2 * ROWS);
      const int arow = sub >> 1;             // 0..91
      const int r0 = (sub & 1) * 25;         // r-half [0,25) / [25,50)
      const int at = (cbase + rr) * SCH - LW + arow;
      float2 xc[NCOL];
      bool zfill = false;
      if (aAct) {
        if (at < 0) {
          zfill = true;
        } else {
          const size_t xrow = (size_t)(((at & 511) << 9) | (at >> 9));
          const float4* src = (const float4*)(Xc + xrow * NCOL);  // 256B aligned
#pragma unroll
          for (int i = 0; i < NCOL / 2; ++i) {
            float4 v = src[i];               // loads issue here, used after C
            xc[2 * i] = make_float2(v.x, v.y);
            xc[2 * i + 1] = make_float2(v.z, v.w);
          }
        }
      }

      // ---- C: out matmul for chunk cbase+rr-2 from statebuf[rr&1] --------
      if (rr >= 2) {
        const int cchunk = cbase + rr - 2;
        const float2* sbuf = statebuf[rr & 1];
#pragma unroll
        for (int k = 0; k < 3; ++k) {
          const int idx = sub + k * 192;     // [0, 576); 512 real tasks
          if (idx < 512) {
            const int tl = idx >> 3;         // 0..63
            const int o0 = (idx & 7) << 2;   // 0,4,...,28
            const float2* srow = &sbuf[tl * LDSTR];
            float ar0 = 0.f, ar1 = 0.f, ar2 = 0.f, ar3 = 0.f;
            float ai0 = 0.f, ai1 = 0.f, ai2 = 0.f, ai3 = 0.f;
            for (int r = 0; r < NR; ++r) {
              const float2 s = srow[r];
              const float w0 = Wout[(o0 + 0) * NR + r];
              const float w1 = Wout[(o0 + 1) * NR + r];
              const float w2 = Wout[(o0 + 2) * NR + r];
              const float w3 = Wout[(o0 + 3) * NR + r];
              ar0 = fmaf(w0, s.x, ar0); ai0 = fmaf(w0, s.y, ai0);
              ar1 = fmaf(w1, s.x, ar1); ai1 = fmaf(w1, s.y, ai1);
              ar2 = fmaf(w2, s.x, ar2); ai2 = fmaf(w2, s.y, ai2);
              ar3 = fmaf(w3, s.x, ar3); ai3 = fmaf(w3, s.y, ai3);
            }
            __half2* orow = &outh[((size_t)cchunk * SCH + tl) * NCOL + o0];
            orow[0] = __floats2half2_rn(ar0, ai0);
            orow[1] = __floats2half2_rn(ar1, ai1);
            orow[2] = __floats2half2_rn(ar2, ai2);
            orow[3] = __floats2half2_rn(ar3, ai3);
          }
        }
      }

      // ---- A (stage 2): project into projbuf[rr&1] -----------------------
      if (aAct) {
        float2* dst = &projbuf[rr & 1][arow * LDSTR];
        if (zfill) {
          for (int r = r0; r < r0 + 25; ++r) dst[r] = make_float2(0.f, 0.f);
        } else {
          for (int r = r0; r < r0 + 25; ++r) {
            float pr = 0.f, pi = 0.f;
#pragma unroll
            for (int c = 0; c < NCOL; ++c) {
              const float w = Win[r * NCOL + c];  // uniform -> scalar broadcast
              pr = fmaf(w, xc[c].x, pr);
              pi = fmaf(w, xc[c].y, pi);
            }
            dst[r] = make_float2(pr, pi);
          }
        }
      }
    } else {
      // ---- B: scan chunk cbase+rr-1: projbuf[(rr-1)&1] -> statebuf[(rr-1)&1]
      if (rr >= 1 && rr <= CPB) {
        const float2* pbuf = projbuf[(rr - 1) & 1];   // read-only
        float2* sbuf = statebuf[(rr - 1) & 1];        // write-only
        float sr = 0.f, si = 0.f;
        float2 p0 = pbuf[0 * LDSTR + rl];
        float2 p1 = pbuf[1 * LDSTR + rl];
        float2 p2 = pbuf[2 * LDSTR + rl];
        for (int i = 0; i < ROWS; ++i) {
          const float2 p = p0;
          p0 = p1;
          p1 = p2;
          const int ip = (i + 3 < ROWS) ? (i + 3) : (ROWS - 1);
          p2 = pbuf[ip * LDSTR + rl];                 // read-only buffer: safe
          esn_step(dv, p.x, p.y, sr, si);
          if (lane < NR && i >= LW)
            sbuf[(i - LW) * LDSTR + lane] = make_float2(sr, si);
        }
      }
    }
    __syncthreads();
  }
}

extern "C" void kernel_launch(void* const* d_in, const int* in_sizes, int n_in,
                              void* d_out, int out_size, void* d_ws, size_t ws_size,
                              hipStream_t stream) {
  const float* X = (const float*)d_in[0];      // [T,32] f32
  const float* Win = (const float*)d_in[1];    // [50,32] f32
  const float* dvec = (const float*)d_in[2];   // [50] f32
  const float* Wout = (const float*)d_in[3];   // [32,50] f32

  float2* Wa = (float2*)d_ws;                  // 67,108,864 B complex region
  dim3 fgrid(512, 2);

  // 1. fwd pass A: X (real) -> ws   (I[kL][nL] at row kL*512+nL)
  fft_passA<-1, 0><<<fgrid, 256, 0, stream>>>(X, Wa, 1.0f);
  // 2. fwd pass B: ws in-place      (Xc digit-swapped)
  fft_passB<-1, false><<<fgrid, 256, 0, stream>>>(Wa, nullptr);
  // 3. fused proj+scan+out: ws(Xc) -> d_out (outc, fp16 complex [T,32])
  esn_scan_fused<<<TLEN / SCH / CPB, 256, 0, stream>>>(Wa, Win, dvec, Wout,
                                                       (__half2*)d_out);
  // 4. inv pass A: d_out (fp16 outc) -> ws  (1/T folded into scale)
  fft_passA<1, 1><<<fgrid, 256, 0, stream>>>(d_out, Wa, 1.0f / 262144.0f);
  // 5. inv pass B: ws -> d_out, REAL part only, float32 [T,32]
  fft_passB<1, true><<<fgrid, 256, 0, stream>>>(Wa, (float*)d_out);

  (void)in_sizes; (void)n_in; (void)out_size; (void)ws_size;
}

// Round 6
// 375.537 us; speedup vs baseline: 2.1435x; 1.9173x over previous
//
#include <hip/hip_runtime.h>
#include <hip/hip_fp16.h>
#include <math.h>

// ESN: FFT(262144) over 32 cols -> fused(proj -> chunked tanh scan -> out matmul)
//      -> IFFT, REAL part only to d_out as float32 [T,32].
//
// v7 (= v6 structure, fp32 LDS):
//  * Scan kernel: recurrence is ELEMENT-WISE in r -> Phase B flattens
//    (chunk, r) onto lanes, 25 lanes per wave (idx = wv*25 + lane), so ALL
//    4 waves scan concurrently. CPB=2, fp32 float2 buffers: LDS = 75,072 B
//    -> 2 blocks/CU (v3-proven residency). v6's fp16 staging FAILED accuracy
//    (7.6e-4 > 2.5e-4): states saturate to |s|~1 where fp16 quantization is
//    4.9e-4 absolute -- NOT sub-dominant. fp32 restores absmax 6.1e-5.
//  * Phase C: wave-uniform out-group mapping (readfirstlane) -> Wout reads
//    are scalar loads; states fp32 from LDS; outc fp16 (validated 5 rounds).
//  * FFT passes: 8 cols/block, padded [512][9] float2 LDS (36,864 B ->
//    4 blocks/CU, was 2). Old [512][16]: butterfly rows hit bank 2*cl ->
//    4-way conflicts; [512][9] spreads rows across banks. Math unchanged.

constexpr int TLEN = 262144;   // 2^18 = 512*512
constexpr int NCOL = 32;       // IN == OUT == 32 columns
constexpr int NR = 50;         // reservoir size
constexpr int SCH = 64;        // scan chunk length (4096 chunks)
constexpr int LW = 28;         // scan warmup rows (validated: absmax unchanged vs 32)
constexpr int ROWS = SCH + LW; // 92 rows per chunk buffer
constexpr int CPB = 2;         // chunks per block (grid 2048)
constexpr int LDSTR = 51;      // LDS row stride in float2 (odd -> spread banks)
constexpr float TWO_PI = 6.28318530717958647692f;

__device__ __forceinline__ unsigned rev9(unsigned x) { return __brev(x) >> 23; }

// In-LDS 512-point radix-2 DIT FFT on 8 interleaved columns.
// lds[512][9] (row padded +1 float2), input bit-reversed (rev9) on load.
// 256 threads: cl = tid&7 (column), bb = tid>>3 (32 butterfly bases).
template <int SIGN>
__device__ __forceinline__ void fft512(float2 (*lds)[9], int tid) {
  const int cl = tid & 7;
  const int bb = tid >> 3;
#pragma unroll
  for (int s = 1; s <= 9; ++s) {
    const int half = 1 << (s - 1);
    const float invm = 1.0f / (float)(1 << s);
#pragma unroll
    for (int i = 0; i < 8; ++i) {
      const int b = bb + (i << 5);            // butterfly slot 0..255
      const int j = b & (half - 1);
      const int g = b >> (s - 1);
      const int i1 = (g << s) + j;
      const int i2 = i1 + half;
      float2 a = lds[i1][cl];
      float2 c = lds[i2][cl];
      float ang = (float)SIGN * TWO_PI * ((float)j * invm);  // j/m exact
      float sw, cw;
      __sincosf(ang, &sw, &cw);
      float2 t = make_float2(c.x * cw - c.y * sw, c.x * sw + c.y * cw);
      lds[i1][cl] = make_float2(a.x + t.x, a.y + t.y);
      lds[i2][cl] = make_float2(a.x - t.x, a.y - t.y);
    }
    __syncthreads();
  }
}

// Pass A: input index n = nL + 512*nH; for block nL, FFT over nH -> kL,
// apply twiddle e^{SIGN*2pi*i*nL*kL/T}, store I[kL][nL] at ws row (kL*512+nL).
// INMODE 0: real float input (forward, X). INMODE 1: half2 complex input
// (inverse, outc in d_out), scaled by `scale` (1/T folded here).
// Grid (512, 4): 8 columns per block.
template <int SIGN, int INMODE>
__global__ __launch_bounds__(256) void fft_passA(const void* __restrict__ vin,
                                                 float2* __restrict__ out,
                                                 float scale) {
  __shared__ float2 lds[512][9];
  const int nL = blockIdx.x;
  const int cg = blockIdx.y;
  const int tid = threadIdx.x;
  const int cl = tid & 7;
  const int cglob = cg * 8 + cl;
#pragma unroll
  for (int i = 0; i < 16; ++i) {
    const int nH = (tid >> 3) + (i << 5);
    const size_t gidx = (size_t)(nL + (nH << 9)) * NCOL + cglob;
    float2 v;
    if (INMODE == 0) {
      v = make_float2(((const float*)vin)[gidx], 0.0f);
    } else {
      const float2 f = __half22float2(((const __half2*)vin)[gidx]);
      v = make_float2(f.x * scale, f.y * scale);
    }
    lds[rev9(nH)][cl] = v;
  }
  __syncthreads();
  fft512<SIGN>(lds, tid);
#pragma unroll
  for (int i = 0; i < 16; ++i) {
    const int kL = (tid >> 3) + (i << 5);
    float2 v = lds[kL][cl];
    const float rev = (float)(nL * kL) * (1.0f / 262144.0f);  // exact (<2^24 / 2^18)
    const float ang = (float)SIGN * TWO_PI * rev;
    float sw, cw;
    __sincosf(ang, &sw, &cw);
    float2 w = make_float2(v.x * cw - v.y * sw, v.x * sw + v.y * cw);
    out[(size_t)(kL * 512 + nL) * NCOL + cglob] = w;
  }
}

// Pass B: for block kL, FFT over nL (rows kL*512+nL) -> kH.
// REALOUT=false (forward): store IN-PLACE at row (kL*512+kH) -> digit-swapped.
// REALOUT=true (inverse): store real part only, natural order, float [T,32].
// Grid (512, 4): 8 columns per block.
template <int SIGN, bool REALOUT>
__global__ __launch_bounds__(256) void fft_passB(float2* __restrict__ buf,
                                                 float* __restrict__ rout) {
  __shared__ float2 lds[512][9];
  const int kL = blockIdx.x;
  const int cg = blockIdx.y;
  const int tid = threadIdx.x;
  const int cl = tid & 7;
  const int cglob = cg * 8 + cl;
#pragma unroll
  for (int i = 0; i < 16; ++i) {
    const int nL = (tid >> 3) + (i << 5);
    lds[rev9(nL)][cl] = buf[(size_t)(kL * 512 + nL) * NCOL + cglob];
  }
  __syncthreads();
  fft512<SIGN>(lds, tid);
#pragma unroll
  for (int i = 0; i < 16; ++i) {
    const int kH = (tid >> 3) + (i << 5);
    if (REALOUT) {
      rout[(size_t)(kL + (kH << 9)) * NCOL + cglob] = lds[kH][cl].x;
    } else {
      buf[(size_t)(kL * 512 + kH) * NCOL + cglob] = lds[kH][cl];
    }
  }
}

// s' = ctanh(p + d*s);  ctanh(x+iy) = (sinh 2x + i sin 2y)/(cosh 2x + cos 2y)
__device__ __forceinline__ void esn_step(float d, float pr, float pi,
                                         float& sr, float& si) {
  const float x = fmaf(d, sr, pr);
  const float y = fmaf(d, si, pi);
  float x2 = 2.0f * x;
  x2 = fminf(fmaxf(x2, -30.0f), 30.0f);  // fp32-saturated beyond this
  const float E = __expf(x2);
  const float Ei = __expf(-x2);
  const float sh = 0.5f * (E - Ei);
  const float ch = 0.5f * (E + Ei);
  float s2, c2;
  __sincosf(2.0f * y, &s2, &c2);
  const float inv = __builtin_amdgcn_rcpf(ch + c2);
  sr = sh * inv;
  si = s2 * inv;
}

// Fused proj -> scan -> out matmul. 256 threads (4 waves), 2 chunks per block.
// Xc is digit-swapped: row of frequency k at ((k&511)<<9)|(k>>9).
// Phase A: threads [0,92) -> chunk 0 rows, [128,220) -> chunk 1 rows (one
//          full 50-r projection per thread, fp32 stores).
// Phase B: lane-parallel scan: lane<25 of wave wv runs task idx = wv*25+lane,
//          chunk idx/50, r idx%50 -- each lane one scalar recurrence over its
//          own LDS column (3-deep rotating prefetch; read row i+3 before the
//          state write of row i; lane-private column -> no hazards). All 4
//          waves (all 4 SIMDs) scan concurrently; x2 blocks/CU.
// Phase C: wave wv -> out-groups {wv, wv+4} (o0 wave-uniform via
//          readfirstlane -> Wout reads are scalar loads); lane = output row.
__global__ __launch_bounds__(256) void esn_scan_fused(
    const float2* __restrict__ Xc, const float* __restrict__ Win,
    const float* __restrict__ dvec, const float* __restrict__ Wout,
    __half2* __restrict__ outh) {
  __shared__ float2 buf[CPB][ROWS * LDSTR];  // 2*92*51*8 = 75,072 B
  const int tid = threadIdx.x;
  const int lane = tid & 63;
  const int wv = tid >> 6;
  const int cbase = blockIdx.x * CPB;

  // Phase A: one thread per row; chunk g = tid>>7, row = tid&127 (< ROWS).
  {
    const int g = tid >> 7;
    const int row = tid & 127;
    if (row < ROWS) {
      const int t = (cbase + g) * SCH - LW + row;
      float2* dst = &buf[g][row * LDSTR];
      if (t < 0) {
        for (int r = 0; r < NR; ++r) dst[r] = make_float2(0.f, 0.f);
      } else {
        const size_t xrow = (size_t)(((t & 511) << 9) | (t >> 9));  // digit-swap
        const float4* src = (const float4*)(Xc + xrow * NCOL);      // 256B aligned
        float2 xc[NCOL];
#pragma unroll
        for (int i = 0; i < NCOL / 2; ++i) {
          float4 v = src[i];
          xc[2 * i] = make_float2(v.x, v.y);
          xc[2 * i + 1] = make_float2(v.z, v.w);
        }
        for (int r = 0; r < NR; ++r) {
          float pr = 0.f, pi = 0.f;
#pragma unroll
          for (int c = 0; c < NCOL; ++c) {
            const float w = Win[r * NCOL + c];  // uniform -> scalar broadcast
            pr = fmaf(w, xc[c].x, pr);
            pi = fmaf(w, xc[c].y, pi);
          }
          dst[r] = make_float2(pr, pi);
        }
      }
    }
  }
  __syncthreads();

  // Phase B: lane-parallel scalar recurrences, 25 tasks per wave.
  if (lane < 25) {
    const int idx = wv * 25 + lane;           // 0..99
    const int c = idx / NR;                   // chunk 0 (waves 0-1) / 1 (2-3)
    const int r = idx - c * NR;
    const float d = dvec[r];
    float2* col = &buf[c][r];                 // lane-private column
    float sr = 0.f, si = 0.f;
    float2 p0 = col[0 * LDSTR];
    float2 p1 = col[1 * LDSTR];
    float2 p2 = col[2 * LDSTR];
    for (int i = 0; i < ROWS; ++i) {
      const float2 p = p0;
      p0 = p1;
      p1 = p2;
      const int ip = (i + 3 < ROWS) ? (i + 3) : (ROWS - 1);
      p2 = col[ip * LDSTR];                   // own column: no hazard
      esn_step(d, p.x, p.y, sr, si);
      if (i >= LW) col[i * LDSTR] = make_float2(sr, si);
    }
  }
  __syncthreads();

  // Phase C: out matmul. Wave wv -> out-groups {wv, wv+4}; lane = output row.
  const int wvu = __builtin_amdgcn_readfirstlane(wv);
#pragma unroll
  for (int p = 0; p < 2; ++p) {
    const int o0 = (wvu + (p << 2)) << 2;     // 0,4,...,28 (wave-uniform)
    for (int c = 0; c < CPB; ++c) {
      const float2* srow = &buf[c][(LW + lane) * LDSTR];
      float ar0 = 0.f, ar1 = 0.f, ar2 = 0.f, ar3 = 0.f;
      float ai0 = 0.f, ai1 = 0.f, ai2 = 0.f, ai3 = 0.f;
      for (int r = 0; r < NR; ++r) {
        const float2 s = srow[r];
        const float w0 = Wout[(o0 + 0) * NR + r];  // uniform -> scalar loads
        const float w1 = Wout[(o0 + 1) * NR + r];
        const float w2 = Wout[(o0 + 2) * NR + r];
        const float w3 = Wout[(o0 + 3) * NR + r];
        ar0 = fmaf(w0, s.x, ar0); ai0 = fmaf(w0, s.y, ai0);
        ar1 = fmaf(w1, s.x, ar1); ai1 = fmaf(w1, s.y, ai1);
        ar2 = fmaf(w2, s.x, ar2); ai2 = fmaf(w2, s.y, ai2);
        ar3 = fmaf(w3, s.x, ar3); ai3 = fmaf(w3, s.y, ai3);
      }
      __half2* orow = &outh[((size_t)(cbase + c) * SCH + lane) * NCOL + o0];
      orow[0] = __floats2half2_rn(ar0, ai0);
      orow[1] = __floats2half2_rn(ar1, ai1);
      orow[2] = __floats2half2_rn(ar2, ai2);
      orow[3] = __floats2half2_rn(ar3, ai3);
    }
  }
}

extern "C" void kernel_launch(void* const* d_in, const int* in_sizes, int n_in,
                              void* d_out, int out_size, void* d_ws, size_t ws_size,
                              hipStream_t stream) {
  const float* X = (const float*)d_in[0];      // [T,32] f32
  const float* Win = (const float*)d_in[1];    // [50,32] f32
  const float* dvec = (const float*)d_in[2];   // [50] f32
  const float* Wout = (const float*)d_in[3];   // [32,50] f32

  float2* Wa = (float2*)d_ws;                  // 67,108,864 B complex region
  dim3 fgrid(512, 4);

  // 1. fwd pass A: X (real) -> ws   (I[kL][nL] at row kL*512+nL)
  fft_passA<-1, 0><<<fgrid, 256, 0, stream>>>(X, Wa, 1.0f);
  // 2. fwd pass B: ws in-place      (Xc digit-swapped)
  fft_passB<-1, false><<<fgrid, 256, 0, stream>>>(Wa, nullptr);
  // 3. fused proj+scan+out: ws(Xc) -> d_out (outc, fp16 complex [T,32])
  esn_scan_fused<<<TLEN / SCH / CPB, 256, 0, stream>>>(Wa, Win, dvec, Wout,
                                                       (__half2*)d_out);
  // 4. inv pass A: d_out (fp16 outc) -> ws  (1/T folded into scale)
  fft_passA<1, 1><<<fgrid, 256, 0, stream>>>(d_out, Wa, 1.0f / 262144.0f);
  // 5. inv pass B: ws -> d_out, REAL part only, float32 [T,32]
  fft_passB<1, true><<<fgrid, 256, 0, stream>>>(Wa, (float*)d_out);

  (void)in_sizes; (void)n_in; (void)out_size; (void)ws_size;
}

// Round 7
// 342.987 us; speedup vs baseline: 2.3469x; 1.0949x over previous
//
#include <hip/hip_runtime.h>
#include <hip/hip_fp16.h>
#include <math.h>

// ESN: FFT(262144) over 32 cols -> fused(proj -> chunked tanh scan -> out matmul)
//      -> IFFT, REAL part only to d_out as float32 [T,32].
//
// v8 = v7 scan kernel (unchanged, 143 us, absmax 6.1e-5) + radix-4 FFT:
//  * fft512 now runs 4 fused double-stages (radix-4 butterflies, one sincos
//    per 4-point group via double-angle; stage-(s+1) twiddles w' and SIGN*i*w')
//    + 1 final radix-2 stage. Halves LDS round-trips (288->160 b64 ops),
//    barriers 10->6, sincos 72->24 per FFT. In-place DIT index layout is
//    identical to the radix-2 version, so pass A/B wrappers are unchanged.
//    Verified by hand at N=4 vs the DFT (both SIGNs).
//  * FFT working sets are L3-resident (67 MB < 256 MB) -> passes are
//    issue/barrier-bound, not HBM-bound; stage-count reduction is the lever.

constexpr int TLEN = 262144;   // 2^18 = 512*512
constexpr int NCOL = 32;       // IN == OUT == 32 columns
constexpr int NR = 50;         // reservoir size
constexpr int SCH = 64;        // scan chunk length (4096 chunks)
constexpr int LW = 28;         // scan warmup rows (validated: absmax unchanged vs 32)
constexpr int ROWS = SCH + LW; // 92 rows per chunk buffer
constexpr int CPB = 2;         // chunks per block (grid 2048)
constexpr int LDSTR = 51;      // LDS row stride in float2 (odd -> spread banks)
constexpr float TWO_PI = 6.28318530717958647692f;

__device__ __forceinline__ unsigned rev9(unsigned x) { return __brev(x) >> 23; }

// In-LDS 512-point DIT FFT on 8 interleaved columns: 4 fused radix-4
// double-stages + 1 final radix-2 stage. lds[512][9] (row padded +1 float2),
// input bit-reversed (rev9) on load. 256 threads: cl = tid&7, bb = tid>>3.
// Index layout identical to 9x radix-2 in-place DIT.
template <int SIGN>
__device__ __forceinline__ void fft512(float2 (*lds)[9], int tid) {
  const int cl = tid & 7;
  const int bb = tid >> 3;                    // 0..31
#pragma unroll
  for (int S = 0; S < 4; ++S) {               // double-stage: radix-2 stages 2S+1, 2S+2
    const int h = 1 << (2 * S);               // 4^S
    const float inv4h = 1.0f / (float)(4 * h);
#pragma unroll
    for (int i = 0; i < 4; ++i) {
      const int q = bb + (i << 5);            // 4-point group id 0..127
      const int j = q & (h - 1);
      const int G = q >> (2 * S);             // q / h
      const int i0 = (G << (2 * S + 2)) + j;  // G*4h + j
      float2 a0 = lds[i0][cl];
      float2 a1 = lds[i0 + h][cl];
      float2 a2 = lds[i0 + 2 * h][cl];
      float2 a3 = lds[i0 + 3 * h][cl];
      // w' = e^{SIGN*2pi*i*j/(4h)} (stage s+1), w = w'^2 (stage s, double-angle)
      const float angp = (float)SIGN * TWO_PI * ((float)j * inv4h);
      float swp, cwp;
      __sincosf(angp, &swp, &cwp);
      const float cw = cwp * cwp - swp * swp;
      const float sw = 2.0f * cwp * swp;
      // stage s: pairs (a0,a1), (a2,a3), twiddle w
      float2 t1 = make_float2(a1.x * cw - a1.y * sw, a1.x * sw + a1.y * cw);
      float2 t3 = make_float2(a3.x * cw - a3.y * sw, a3.x * sw + a3.y * cw);
      float2 u0 = make_float2(a0.x + t1.x, a0.y + t1.y);
      float2 u1 = make_float2(a0.x - t1.x, a0.y - t1.y);
      float2 u2 = make_float2(a2.x + t3.x, a2.y + t3.y);
      float2 u3 = make_float2(a2.x - t3.x, a2.y - t3.y);
      // stage s+1: pair (u0,u2) twiddle w'; pair (u1,u3) twiddle SIGN*i*w'
      float2 r2 = make_float2(u2.x * cwp - u2.y * swp, u2.x * swp + u2.y * cwp);
      float2 r3 = make_float2(u3.x * cwp - u3.y * swp, u3.x * swp + u3.y * cwp);
      const float2 s3 = (SIGN < 0) ? make_float2(r3.y, -r3.x)   // *(-i)
                                   : make_float2(-r3.y, r3.x);  // *(+i)
      lds[i0][cl]         = make_float2(u0.x + r2.x, u0.y + r2.y);
      lds[i0 + 2 * h][cl] = make_float2(u0.x - r2.x, u0.y - r2.y);
      lds[i0 + h][cl]     = make_float2(u1.x + s3.x, u1.y + s3.y);
      lds[i0 + 3 * h][cl] = make_float2(u1.x - s3.x, u1.y - s3.y);
    }
    __syncthreads();
  }
  // final radix-2 stage (s=9): half = 256
  {
#pragma unroll
    for (int i = 0; i < 8; ++i) {
      const int j = bb + (i << 5);            // butterfly 0..255; i1 = j
      float2 a = lds[j][cl];
      float2 c = lds[j + 256][cl];
      const float ang = (float)SIGN * TWO_PI * ((float)j * (1.0f / 512.0f));
      float sw, cw;
      __sincosf(ang, &sw, &cw);
      float2 t = make_float2(c.x * cw - c.y * sw, c.x * sw + c.y * cw);
      lds[j][cl]       = make_float2(a.x + t.x, a.y + t.y);
      lds[j + 256][cl] = make_float2(a.x - t.x, a.y - t.y);
    }
    __syncthreads();
  }
}

// Pass A: input index n = nL + 512*nH; for block nL, FFT over nH -> kL,
// apply twiddle e^{SIGN*2pi*i*nL*kL/T}, store I[kL][nL] at ws row (kL*512+nL).
// INMODE 0: real float input (forward, X). INMODE 1: half2 complex input
// (inverse, outc in d_out), scaled by `scale` (1/T folded here).
// Grid (512, 4): 8 columns per block.
template <int SIGN, int INMODE>
__global__ __launch_bounds__(256) void fft_passA(const void* __restrict__ vin,
                                                 float2* __restrict__ out,
                                                 float scale) {
  __shared__ float2 lds[512][9];
  const int nL = blockIdx.x;
  const int cg = blockIdx.y;
  const int tid = threadIdx.x;
  const int cl = tid & 7;
  const int cglob = cg * 8 + cl;
#pragma unroll
  for (int i = 0; i < 16; ++i) {
    const int nH = (tid >> 3) + (i << 5);
    const size_t gidx = (size_t)(nL + (nH << 9)) * NCOL + cglob;
    float2 v;
    if (INMODE == 0) {
      v = make_float2(((const float*)vin)[gidx], 0.0f);
    } else {
      const float2 f = __half22float2(((const __half2*)vin)[gidx]);
      v = make_float2(f.x * scale, f.y * scale);
    }
    lds[rev9(nH)][cl] = v;
  }
  __syncthreads();
  fft512<SIGN>(lds, tid);
#pragma unroll
  for (int i = 0; i < 16; ++i) {
    const int kL = (tid >> 3) + (i << 5);
    float2 v = lds[kL][cl];
    const float rev = (float)(nL * kL) * (1.0f / 262144.0f);  // exact (<2^24 / 2^18)
    const float ang = (float)SIGN * TWO_PI * rev;
    float sw, cw;
    __sincosf(ang, &sw, &cw);
    float2 w = make_float2(v.x * cw - v.y * sw, v.x * sw + v.y * cw);
    out[(size_t)(kL * 512 + nL) * NCOL + cglob] = w;
  }
}

// Pass B: for block kL, FFT over nL (rows kL*512+nL) -> kH.
// REALOUT=false (forward): store IN-PLACE at row (kL*512+kH) -> digit-swapped.
// REALOUT=true (inverse): store real part only, natural order, float [T,32].
// Grid (512, 4): 8 columns per block.
template <int SIGN, bool REALOUT>
__global__ __launch_bounds__(256) void fft_passB(float2* __restrict__ buf,
                                                 float* __restrict__ rout) {
  __shared__ float2 lds[512][9];
  const int kL = blockIdx.x;
  const int cg = blockIdx.y;
  const int tid = threadIdx.x;
  const int cl = tid & 7;
  const int cglob = cg * 8 + cl;
#pragma unroll
  for (int i = 0; i < 16; ++i) {
    const int nL = (tid >> 3) + (i << 5);
    lds[rev9(nL)][cl] = buf[(size_t)(kL * 512 + nL) * NCOL + cglob];
  }
  __syncthreads();
  fft512<SIGN>(lds, tid);
#pragma unroll
  for (int i = 0; i < 16; ++i) {
    const int kH = (tid >> 3) + (i << 5);
    if (REALOUT) {
      rout[(size_t)(kL + (kH << 9)) * NCOL + cglob] = lds[kH][cl].x;
    } else {
      buf[(size_t)(kL * 512 + kH) * NCOL + cglob] = lds[kH][cl];
    }
  }
}

// s' = ctanh(p + d*s);  ctanh(x+iy) = (sinh 2x + i sin 2y)/(cosh 2x + cos 2y)
__device__ __forceinline__ void esn_step(float d, float pr, float pi,
                                         float& sr, float& si) {
  const float x = fmaf(d, sr, pr);
  const float y = fmaf(d, si, pi);
  float x2 = 2.0f * x;
  x2 = fminf(fmaxf(x2, -30.0f), 30.0f);  // fp32-saturated beyond this
  const float E = __expf(x2);
  const float Ei = __expf(-x2);
  const float sh = 0.5f * (E - Ei);
  const float ch = 0.5f * (E + Ei);
  float s2, c2;
  __sincosf(2.0f * y, &s2, &c2);
  const float inv = __builtin_amdgcn_rcpf(ch + c2);
  sr = sh * inv;
  si = s2 * inv;
}

// Fused proj -> scan -> out matmul. 256 threads (4 waves), 2 chunks per block.
// Xc is digit-swapped: row of frequency k at ((k&511)<<9)|(k>>9).
// Phase A: threads [0,92) -> chunk 0 rows, [128,220) -> chunk 1 rows (one
//          full 50-r projection per thread, fp32 stores).
// Phase B: lane-parallel scan: lane<25 of wave wv runs task idx = wv*25+lane,
//          chunk idx/50, r idx%50 -- each lane one scalar recurrence over its
//          own LDS column (3-deep rotating prefetch; read row i+3 before the
//          state write of row i; lane-private column -> no hazards). All 4
//          waves (all 4 SIMDs) scan concurrently; x2 blocks/CU.
// Phase C: wave wv -> out-groups {wv, wv+4} (o0 wave-uniform via
//          readfirstlane -> Wout reads are scalar loads); lane = output row.
__global__ __launch_bounds__(256) void esn_scan_fused(
    const float2* __restrict__ Xc, const float* __restrict__ Win,
    const float* __restrict__ dvec, const float* __restrict__ Wout,
    __half2* __restrict__ outh) {
  __shared__ float2 buf[CPB][ROWS * LDSTR];  // 2*92*51*8 = 75,072 B
  const int tid = threadIdx.x;
  const int lane = tid & 63;
  const int wv = tid >> 6;
  const int cbase = blockIdx.x * CPB;

  // Phase A: one thread per row; chunk g = tid>>7, row = tid&127 (< ROWS).
  {
    const int g = tid >> 7;
    const int row = tid & 127;
    if (row < ROWS) {
      const int t = (cbase + g) * SCH - LW + row;
      float2* dst = &buf[g][row * LDSTR];
      if (t < 0) {
        for (int r = 0; r < NR; ++r) dst[r] = make_float2(0.f, 0.f);
      } else {
        const size_t xrow = (size_t)(((t & 511) << 9) | (t >> 9));  // digit-swap
        const float4* src = (const float4*)(Xc + xrow * NCOL);      // 256B aligned
        float2 xc[NCOL];
#pragma unroll
        for (int i = 0; i < NCOL / 2; ++i) {
          float4 v = src[i];
          xc[2 * i] = make_float2(v.x, v.y);
          xc[2 * i + 1] = make_float2(v.z, v.w);
        }
        for (int r = 0; r < NR; ++r) {
          float pr = 0.f, pi = 0.f;
#pragma unroll
          for (int c = 0; c < NCOL; ++c) {
            const float w = Win[r * NCOL + c];  // uniform -> scalar broadcast
            pr = fmaf(w, xc[c].x, pr);
            pi = fmaf(w, xc[c].y, pi);
          }
          dst[r] = make_float2(pr, pi);
        }
      }
    }
  }
  __syncthreads();

  // Phase B: lane-parallel scalar recurrences, 25 tasks per wave.
  if (lane < 25) {
    const int idx = wv * 25 + lane;           // 0..99
    const int c = idx / NR;                   // chunk 0 (waves 0-1) / 1 (2-3)
    const int r = idx - c * NR;
    const float d = dvec[r];
    float2* col = &buf[c][r];                 // lane-private column
    float sr = 0.f, si = 0.f;
    float2 p0 = col[0 * LDSTR];
    float2 p1 = col[1 * LDSTR];
    float2 p2 = col[2 * LDSTR];
    for (int i = 0; i < ROWS; ++i) {
      const float2 p = p0;
      p0 = p1;
      p1 = p2;
      const int ip = (i + 3 < ROWS) ? (i + 3) : (ROWS - 1);
      p2 = col[ip * LDSTR];                   // own column: no hazard
      esn_step(d, p.x, p.y, sr, si);
      if (i >= LW) col[i * LDSTR] = make_float2(sr, si);
    }
  }
  __syncthreads();

  // Phase C: out matmul. Wave wv -> out-groups {wv, wv+4}; lane = output row.
  const int wvu = __builtin_amdgcn_readfirstlane(wv);
#pragma unroll
  for (int p = 0; p < 2; ++p) {
    const int o0 = (wvu + (p << 2)) << 2;     // 0,4,...,28 (wave-uniform)
    for (int c = 0; c < CPB; ++c) {
      const float2* srow = &buf[c][(LW + lane) * LDSTR];
      float ar0 = 0.f, ar1 = 0.f, ar2 = 0.f, ar3 = 0.f;
      float ai0 = 0.f, ai1 = 0.f, ai2 = 0.f, ai3 = 0.f;
      for (int r = 0; r < NR; ++r) {
        const float2 s = srow[r];
        const float w0 = Wout[(o0 + 0) * NR + r];  // uniform -> scalar loads
        const float w1 = Wout[(o0 + 1) * NR + r];
        const float w2 = Wout[(o0 + 2) * NR + r];
        const float w3 = Wout[(o0 + 3) * NR + r];
        ar0 = fmaf(w0, s.x, ar0); ai0 = fmaf(w0, s.y, ai0);
        ar1 = fmaf(w1, s.x, ar1); ai1 = fmaf(w1, s.y, ai1);
        ar2 = fmaf(w2, s.x, ar2); ai2 = fmaf(w2, s.y, ai2);
        ar3 = fmaf(w3, s.x, ar3); ai3 = fmaf(w3, s.y, ai3);
      }
      __half2* orow = &outh[((size_t)(cbase + c) * SCH + lane) * NCOL + o0];
      orow[0] = __floats2half2_rn(ar0, ai0);
      orow[1] = __floats2half2_rn(ar1, ai1);
      orow[2] = __floats2half2_rn(ar2, ai2);
      orow[3] = __floats2half2_rn(ar3, ai3);
    }
  }
}

extern "C" void kernel_launch(void* const* d_in, const int* in_sizes, int n_in,
                              void* d_out, int out_size, void* d_ws, size_t ws_size,
                              hipStream_t stream) {
  const float* X = (const float*)d_in[0];      // [T,32] f32
  const float* Win = (const float*)d_in[1];    // [50,32] f32
  const float* dvec = (const float*)d_in[2];   // [50] f32
  const float* Wout = (const float*)d_in[3];   // [32,50] f32

  float2* Wa = (float2*)d_ws;                  // 67,108,864 B complex region
  dim3 fgrid(512, 4);

  // 1. fwd pass A: X (real) -> ws   (I[kL][nL] at row kL*512+nL)
  fft_passA<-1, 0><<<fgrid, 256, 0, stream>>>(X, Wa, 1.0f);
  // 2. fwd pass B: ws in-place      (Xc digit-swapped)
  fft_passB<-1, false><<<fgrid, 256, 0, stream>>>(Wa, nullptr);
  // 3. fused proj+scan+out: ws(Xc) -> d_out (outc, fp16 complex [T,32])
  esn_scan_fused<<<TLEN / SCH / CPB, 256, 0, stream>>>(Wa, Win, dvec, Wout,
                                                       (__half2*)d_out);
  // 4. inv pass A: d_out (fp16 outc) -> ws  (1/T folded into scale)
  fft_passA<1, 1><<<fgrid, 256, 0, stream>>>(d_out, Wa, 1.0f / 262144.0f);
  // 5. inv pass B: ws -> d_out, REAL part only, float32 [T,32]
  fft_passB<1, true><<<fgrid, 256, 0, stream>>>(Wa, (float*)d_out);

  (void)in_sizes; (void)n_in; (void)out_size; (void)ws_size;
}

// Round 8
// 286.078 us; speedup vs baseline: 2.8137x; 1.1989x over previous
//
#include <hip/hip_runtime.h>
#include <hip/hip_fp16.h>
#include <math.h>

// ESN: FFT(262144) over 32 cols -> fused(proj -> chunked tanh scan -> out matmul)
//      -> IFFT, REAL part only to d_out as float32 [T,32].
//
// v9 = v8 + real-packing: ALL FFT passes run on 16 PACKED complex columns.
//  * Forward: z_c = x_{2c} + i*x_{2c+1} (a float2 load from real X). The scan's
//    Phase A unpacks via conjugate symmetry using row k and mirror row N-k:
//      A[k] = (Z[k]+conj(Z[N-k]))/2,  B[k] = -i(Z[k]-conj(Z[N-k]))/2.
//  * Inverse: only Re(ifft) is kept, so U[k]=(V[k]+conj(V[N-k]))/2 (whose ifft
//    is Re(ifft(V))) packs two output columns as P = U_a + i*U_b; inv passA
//    builds P from fp16 outc rows k and N-k; inv passB stores (y_2c, y_2c+1)
//    as one contiguous float2.
//  * FFT grids (512,4)->(512,2): half the blocks, identical per-block work.
//    ws halves to 33.5 MB (better L3 residency). Scan B/C unchanged (v7,
//    143 us, absmax 6.1e-5); Phase A adds mirror-row read + unpack VALU.

constexpr int TLEN = 262144;   // 2^18 = 512*512
constexpr int NCOL = 32;       // IN == OUT == 32 real columns
constexpr int NCOLP = 16;      // packed complex columns
constexpr int NR = 50;         // reservoir size
constexpr int SCH = 64;        // scan chunk length (4096 chunks)
constexpr int LW = 28;         // scan warmup rows (validated: absmax unchanged vs 32)
constexpr int ROWS = SCH + LW; // 92 rows per chunk buffer
constexpr int CPB = 2;         // chunks per block (grid 2048)
constexpr int LDSTR = 51;      // LDS row stride in float2 (odd -> spread banks)
constexpr float TWO_PI = 6.28318530717958647692f;

__device__ __forceinline__ unsigned rev9(unsigned x) { return __brev(x) >> 23; }

// In-LDS 512-point DIT FFT on 8 interleaved columns: 4 fused radix-4
// double-stages + 1 final radix-2 stage. lds[512][9] (row padded +1 float2),
// input bit-reversed (rev9) on load. 256 threads: cl = tid&7, bb = tid>>3.
template <int SIGN>
__device__ __forceinline__ void fft512(float2 (*lds)[9], int tid) {
  const int cl = tid & 7;
  const int bb = tid >> 3;                    // 0..31
#pragma unroll
  for (int S = 0; S < 4; ++S) {               // radix-2 stages 2S+1, 2S+2 fused
    const int h = 1 << (2 * S);               // 4^S
    const float inv4h = 1.0f / (float)(4 * h);
#pragma unroll
    for (int i = 0; i < 4; ++i) {
      const int q = bb + (i << 5);            // 4-point group id 0..127
      const int j = q & (h - 1);
      const int G = q >> (2 * S);             // q / h
      const int i0 = (G << (2 * S + 2)) + j;  // G*4h + j
      float2 a0 = lds[i0][cl];
      float2 a1 = lds[i0 + h][cl];
      float2 a2 = lds[i0 + 2 * h][cl];
      float2 a3 = lds[i0 + 3 * h][cl];
      // w' = e^{SIGN*2pi*i*j/(4h)} (stage s+1), w = w'^2 (double-angle)
      const float angp = (float)SIGN * TWO_PI * ((float)j * inv4h);
      float swp, cwp;
      __sincosf(angp, &swp, &cwp);
      const float cw = cwp * cwp - swp * swp;
      const float sw = 2.0f * cwp * swp;
      float2 t1 = make_float2(a1.x * cw - a1.y * sw, a1.x * sw + a1.y * cw);
      float2 t3 = make_float2(a3.x * cw - a3.y * sw, a3.x * sw + a3.y * cw);
      float2 u0 = make_float2(a0.x + t1.x, a0.y + t1.y);
      float2 u1 = make_float2(a0.x - t1.x, a0.y - t1.y);
      float2 u2 = make_float2(a2.x + t3.x, a2.y + t3.y);
      float2 u3 = make_float2(a2.x - t3.x, a2.y - t3.y);
      float2 r2 = make_float2(u2.x * cwp - u2.y * swp, u2.x * swp + u2.y * cwp);
      float2 r3 = make_float2(u3.x * cwp - u3.y * swp, u3.x * swp + u3.y * cwp);
      const float2 s3 = (SIGN < 0) ? make_float2(r3.y, -r3.x)   // *(-i)
                                   : make_float2(-r3.y, r3.x);  // *(+i)
      lds[i0][cl]         = make_float2(u0.x + r2.x, u0.y + r2.y);
      lds[i0 + 2 * h][cl] = make_float2(u0.x - r2.x, u0.y - r2.y);
      lds[i0 + h][cl]     = make_float2(u1.x + s3.x, u1.y + s3.y);
      lds[i0 + 3 * h][cl] = make_float2(u1.x - s3.x, u1.y - s3.y);
    }
    __syncthreads();
  }
  // final radix-2 stage (s=9): half = 256
  {
#pragma unroll
    for (int i = 0; i < 8; ++i) {
      const int j = bb + (i << 5);            // butterfly 0..255; i1 = j
      float2 a = lds[j][cl];
      float2 c = lds[j + 256][cl];
      const float ang = (float)SIGN * TWO_PI * ((float)j * (1.0f / 512.0f));
      float sw, cw;
      __sincosf(ang, &sw, &cw);
      float2 t = make_float2(c.x * cw - c.y * sw, c.x * sw + c.y * cw);
      lds[j][cl]       = make_float2(a.x + t.x, a.y + t.y);
      lds[j + 256][cl] = make_float2(a.x - t.x, a.y - t.y);
    }
    __syncthreads();
  }
}

// Pass A (packed, 16 cols): input index n = nL + 512*nH; for block nL, FFT
// over nH -> kL, twiddle e^{SIGN*2pi*i*nL*kL/T}, store at ws row (kL*512+nL).
// INMODE 0 (forward): packed float2 load from real X [T,32] -> z = x2c+i*x2c1.
// INMODE 1 (inverse): build P[k] = (Va[k]+conj(Va[N-k]))/2 + i*(Vb[k]+conj(
//   Vb[N-k]))/2 from fp16 outc [T,32]; `scale` carries 0.5/T.
// Grid (512, 2): 8 packed columns per block.
template <int SIGN, int INMODE>
__global__ __launch_bounds__(256) void fft_passA(const void* __restrict__ vin,
                                                 float2* __restrict__ out,
                                                 float scale) {
  __shared__ float2 lds[512][9];
  const int nL = blockIdx.x;
  const int cg = blockIdx.y;
  const int tid = threadIdx.x;
  const int cl = tid & 7;
  const int cglob = cg * 8 + cl;              // packed col 0..15
#pragma unroll
  for (int i = 0; i < 16; ++i) {
    const int nH = (tid >> 3) + (i << 5);
    const size_t k = (size_t)(nL + (nH << 9));
    float2 v;
    if (INMODE == 0) {
      v = ((const float2*)vin)[k * NCOLP + cglob];   // (x_{2c}, x_{2c+1})
    } else {
      const size_t m = (TLEN - k) & (TLEN - 1);      // mirror frequency
      const __half2* hin = (const __half2*)vin;
      const float2 va = __half22float2(hin[k * NCOL + 2 * cglob]);
      const float2 vb = __half22float2(hin[k * NCOL + 2 * cglob + 1]);
      const float2 wa = __half22float2(hin[m * NCOL + 2 * cglob]);
      const float2 wb = __half22float2(hin[m * NCOL + 2 * cglob + 1]);
      // P = 0.5*((va+conj(wa)) + i*(vb+conj(wb))); 0.5 folded into scale
      v = make_float2(scale * (va.x + wa.x - vb.y + wb.y),
                      scale * (va.y - wa.y + vb.x + wb.x));
    }
    lds[rev9(nH)][cl] = v;
  }
  __syncthreads();
  fft512<SIGN>(lds, tid);
#pragma unroll
  for (int i = 0; i < 16; ++i) {
    const int kL = (tid >> 3) + (i << 5);
    float2 v = lds[kL][cl];
    const float rev = (float)(nL * kL) * (1.0f / 262144.0f);  // exact (<2^24 / 2^18)
    const float ang = (float)SIGN * TWO_PI * rev;
    float sw, cw;
    __sincosf(ang, &sw, &cw);
    float2 w = make_float2(v.x * cw - v.y * sw, v.x * sw + v.y * cw);
    out[(size_t)(kL * 512 + nL) * NCOLP + cglob] = w;
  }
}

// Pass B (packed): for block kL, FFT over nL (rows kL*512+nL) -> kH.
// REALOUT=false (forward): store IN-PLACE at row (kL*512+kH) -> digit-swapped.
// REALOUT=true (inverse): lds value = (y_{2c}, y_{2c+1}) real pair -> one
//   contiguous float2 store into d_out [T,32] f32, natural order.
// Grid (512, 2): 8 packed columns per block.
template <int SIGN, bool REALOUT>
__global__ __launch_bounds__(256) void fft_passB(float2* __restrict__ buf,
                                                 float* __restrict__ rout) {
  __shared__ float2 lds[512][9];
  const int kL = blockIdx.x;
  const int cg = blockIdx.y;
  const int tid = threadIdx.x;
  const int cl = tid & 7;
  const int cglob = cg * 8 + cl;
#pragma unroll
  for (int i = 0; i < 16; ++i) {
    const int nL = (tid >> 3) + (i << 5);
    lds[rev9(nL)][cl] = buf[(size_t)(kL * 512 + nL) * NCOLP + cglob];
  }
  __syncthreads();
  fft512<SIGN>(lds, tid);
#pragma unroll
  for (int i = 0; i < 16; ++i) {
    const int kH = (tid >> 3) + (i << 5);
    if (REALOUT) {
      ((float2*)rout)[(size_t)(kL + (kH << 9)) * NCOLP + cglob] = lds[kH][cl];
    } else {
      buf[(size_t)(kL * 512 + kH) * NCOLP + cglob] = lds[kH][cl];
    }
  }
}

// s' = ctanh(p + d*s);  ctanh(x+iy) = (sinh 2x + i sin 2y)/(cosh 2x + cos 2y)
__device__ __forceinline__ void esn_step(float d, float pr, float pi,
                                         float& sr, float& si) {
  const float x = fmaf(d, sr, pr);
  const float y = fmaf(d, si, pi);
  float x2 = 2.0f * x;
  x2 = fminf(fmaxf(x2, -30.0f), 30.0f);  // fp32-saturated beyond this
  const float E = __expf(x2);
  const float Ei = __expf(-x2);
  const float sh = 0.5f * (E - Ei);
  const float ch = 0.5f * (E + Ei);
  float s2, c2;
  __sincosf(2.0f * y, &s2, &c2);
  const float inv = __builtin_amdgcn_rcpf(ch + c2);
  sr = sh * inv;
  si = s2 * inv;
}

// Fused proj -> scan -> out matmul. 256 threads (4 waves), 2 chunks per block.
// Xc is PACKED [T,16] and digit-swapped: row of freq k at ((k&511)<<9)|(k>>9).
// Phase A: one thread per row; reads packed row k AND mirror row N-k, unpacks
//          32 complex spectrum values via conjugate symmetry, then projects.
// Phase B: lane-parallel scan (unchanged from v7): lane<25 of wave wv runs
//          task idx = wv*25+lane over its own LDS column; all 4 waves active.
// Phase C: wave wv -> out-groups {wv, wv+4} (wave-uniform scalar Wout loads).
__global__ __launch_bounds__(256) void esn_scan_fused(
    const float2* __restrict__ Xc, const float* __restrict__ Win,
    const float* __restrict__ dvec, const float* __restrict__ Wout,
    __half2* __restrict__ outh) {
  __shared__ float2 buf[CPB][ROWS * LDSTR];  // 2*92*51*8 = 75,072 B
  const int tid = threadIdx.x;
  const int lane = tid & 63;
  const int wv = tid >> 6;
  const int cbase = blockIdx.x * CPB;

  // Phase A: one thread per row; chunk g = tid>>7, row = tid&127 (< ROWS).
  {
    const int g = tid >> 7;
    const int row = tid & 127;
    if (row < ROWS) {
      const int t = (cbase + g) * SCH - LW + row;
      float2* dst = &buf[g][row * LDSTR];
      if (t < 0) {
        for (int r = 0; r < NR; ++r) dst[r] = make_float2(0.f, 0.f);
      } else {
        const size_t xrow = (size_t)(((t & 511) << 9) | (t >> 9));  // digit-swap
        const int tm = (TLEN - t) & (TLEN - 1);                     // mirror freq
        const size_t xrowm = (size_t)(((tm & 511) << 9) | (tm >> 9));
        const float4* src = (const float4*)(Xc + xrow * NCOLP);     // 128B align
        const float4* srcm = (const float4*)(Xc + xrowm * NCOLP);
        float4 z4[8], m4[8];
#pragma unroll
        for (int i = 0; i < 8; ++i) { z4[i] = src[i]; m4[i] = srcm[i]; }
        float2 xc[NCOL];
#pragma unroll
        for (int c = 0; c < NCOLP; ++c) {
          const float zx = (c & 1) ? z4[c >> 1].z : z4[c >> 1].x;
          const float zy = (c & 1) ? z4[c >> 1].w : z4[c >> 1].y;
          const float mx = (c & 1) ? m4[c >> 1].z : m4[c >> 1].x;
          const float my = (c & 1) ? m4[c >> 1].w : m4[c >> 1].y;
          // A = (Z + conj(Zm))/2 ; B = -i(Z - conj(Zm))/2
          xc[2 * c]     = make_float2(0.5f * (zx + mx), 0.5f * (zy - my));
          xc[2 * c + 1] = make_float2(0.5f * (zy + my), 0.5f * (mx - zx));
        }
        for (int r = 0; r < NR; ++r) {
          float pr = 0.f, pi = 0.f;
#pragma unroll
          for (int c = 0; c < NCOL; ++c) {
            const float w = Win[r * NCOL + c];  // uniform -> scalar broadcast
            pr = fmaf(w, xc[c].x, pr);
            pi = fmaf(w, xc[c].y, pi);
          }
          dst[r] = make_float2(pr, pi);
        }
      }
    }
  }
  __syncthreads();

  // Phase B: lane-parallel scalar recurrences, 25 tasks per wave (v7).
  if (lane < 25) {
    const int idx = wv * 25 + lane;           // 0..99
    const int c = idx / NR;                   // chunk 0 (waves 0-1) / 1 (2-3)
    const int r = idx - c * NR;
    const float d = dvec[r];
    float2* col = &buf[c][r];                 // lane-private column
    float sr = 0.f, si = 0.f;
    float2 p0 = col[0 * LDSTR];
    float2 p1 = col[1 * LDSTR];
    float2 p2 = col[2 * LDSTR];
    for (int i = 0; i < ROWS; ++i) {
      const float2 p = p0;
      p0 = p1;
      p1 = p2;
      const int ip = (i + 3 < ROWS) ? (i + 3) : (ROWS - 1);
      p2 = col[ip * LDSTR];                   // own column: no hazard
      esn_step(d, p.x, p.y, sr, si);
      if (i >= LW) col[i * LDSTR] = make_float2(sr, si);
    }
  }
  __syncthreads();

  // Phase C: out matmul. Wave wv -> out-groups {wv, wv+4}; lane = output row.
  const int wvu = __builtin_amdgcn_readfirstlane(wv);
#pragma unroll
  for (int p = 0; p < 2; ++p) {
    const int o0 = (wvu + (p << 2)) << 2;     // 0,4,...,28 (wave-uniform)
    for (int c = 0; c < CPB; ++c) {
      const float2* srow = &buf[c][(LW + lane) * LDSTR];
      float ar0 = 0.f, ar1 = 0.f, ar2 = 0.f, ar3 = 0.f;
      float ai0 = 0.f, ai1 = 0.f, ai2 = 0.f, ai3 = 0.f;
      for (int r = 0; r < NR; ++r) {
        const float2 s = srow[r];
        const float w0 = Wout[(o0 + 0) * NR + r];  // uniform -> scalar loads
        const float w1 = Wout[(o0 + 1) * NR + r];
        const float w2 = Wout[(o0 + 2) * NR + r];
        const float w3 = Wout[(o0 + 3) * NR + r];
        ar0 = fmaf(w0, s.x, ar0); ai0 = fmaf(w0, s.y, ai0);
        ar1 = fmaf(w1, s.x, ar1); ai1 = fmaf(w1, s.y, ai1);
        ar2 = fmaf(w2, s.x, ar2); ai2 = fmaf(w2, s.y, ai2);
        ar3 = fmaf(w3, s.x, ar3); ai3 = fmaf(w3, s.y, ai3);
      }
      __half2* orow = &outh[((size_t)(cbase + c) * SCH + lane) * NCOL + o0];
      orow[0] = __floats2half2_rn(ar0, ai0);
      orow[1] = __floats2half2_rn(ar1, ai1);
      orow[2] = __floats2half2_rn(ar2, ai2);
      orow[3] = __floats2half2_rn(ar3, ai3);
    }
  }
}

extern "C" void kernel_launch(void* const* d_in, const int* in_sizes, int n_in,
                              void* d_out, int out_size, void* d_ws, size_t ws_size,
                              hipStream_t stream) {
  const float* X = (const float*)d_in[0];      // [T,32] f32
  const float* Win = (const float*)d_in[1];    // [50,32] f32
  const float* dvec = (const float*)d_in[2];   // [50] f32
  const float* Wout = (const float*)d_in[3];   // [32,50] f32

  float2* Wa = (float2*)d_ws;                  // packed ws: [T,16] complex, 33.5 MB
  dim3 fgrid(512, 2);

  // 1. fwd pass A: X packed (x2c + i*x2c1) -> ws  (row kL*512+nL)
  fft_passA<-1, 0><<<fgrid, 256, 0, stream>>>(X, Wa, 1.0f);
  // 2. fwd pass B: ws in-place (packed Zc, digit-swapped)
  fft_passB<-1, false><<<fgrid, 256, 0, stream>>>(Wa, nullptr);
  // 3. fused unpack+proj+scan+out: ws -> d_out (outc, fp16 complex [T,32])
  esn_scan_fused<<<TLEN / SCH / CPB, 256, 0, stream>>>(Wa, Win, dvec, Wout,
                                                       (__half2*)d_out);
  // 4. inv pass A: d_out (fp16 outc, mirror-paired) -> ws  (0.5/T in scale)
  fft_passA<1, 1><<<fgrid, 256, 0, stream>>>(d_out, Wa, 0.5f / 262144.0f);
  // 5. inv pass B: ws -> d_out, packed real pairs, float32 [T,32]
  fft_passB<1, true><<<fgrid, 256, 0, stream>>>(Wa, (float*)d_out);

  (void)in_sizes; (void)n_in; (void)out_size; (void)ws_size;
}